// Round 2
// 618.113 us; speedup vs baseline: 1.0214x; 1.0214x over previous
//
#include <hip/hip_runtime.h>
#include <math.h>

// ---------------------------------------------------------------------------
// MultiTaskGAT: 2x GATConv(8 heads x 32ch, concat) + 4 task heads (1 head)
// N=50000 nodes, E=800000 edges (+N self loops), F_IN=128, DH=256.
//
// R2: unnormalized softmax (exp hoisted), single-pass gathers.
// R3: gather loops unrolled x4 (latency/MLP).
// R4: GEMMs -> bf16 MFMA hi/lo split.
// R5: gathers read bf16 feature rows.
// R6: alphas folded into GEMM B-columns; gathers emit GEMM A-operand;
//     log_softmax fused into task gather.
// R7: fused-softmax epilogue de-LDS'd; A-operand single bf16 (2-term MFMA).
// R8: gather addressing scalarized (readfirstlane src -> SALU row math,
//     saddr gathers), CSR rows padded to x4, shuffle-based scan kernel.
// R9: latency fix for all gathers: per-wave CSR index preload (1 coalesced
//     load + v_readlane extraction -> no per-group dependent CSR load);
//     edge weights transposed to [head|task][slot] planes (float4 loads);
//     task channel layout padded to 224 (starts 0,12,44,104) so each lane
//     owns one task (no cndmask weight selects, single ws, light epilogue);
//     8-edge groups with loads issued ahead of consumption.
// R10: resubmit of R9 (round-1 bench was an infra failure: container died
//     before any kernel ran; no counters produced).
// ---------------------------------------------------------------------------

#define NEG_SLOPE 0.2f

typedef short s8v __attribute__((ext_vector_type(8)));
typedef short s4v __attribute__((ext_vector_type(4)));
typedef float f4v __attribute__((ext_vector_type(4)));

__device__ __forceinline__ short f2bf(float x) {
    unsigned u = __float_as_uint(x);
    u += 0x7fffu + ((u >> 16) & 1u);
    return (short)(u >> 16);
}
__device__ __forceinline__ float bf2f(short b) {
    return __uint_as_float(((unsigned)(unsigned short)b) << 16);
}
__device__ __forceinline__ void split2(float x, short& h, short& l) {
    h = f2bf(x);
    l = f2bf(x - bf2f(h));
}
__device__ __forceinline__ float4 bf4_to_f4(s4v v) {
    return make_float4(bf2f(v[0]), bf2f(v[1]), bf2f(v[2]), bf2f(v[3]));
}
// extract edge e's src index from the wave-preloaded index vector; pad
// slots hold -1 -> clamp to row 0 (their weight is 0).
__device__ __forceinline__ int rl_at(int v, int e) {
    int s = __builtin_amdgcn_readlane(v, e);
    return s < 0 ? 0 : s;
}

// ---------------- CSR build ----------------

__global__ void init_kernel(int* __restrict__ deg, int* __restrict__ cursor, int n) {
    int i = blockIdx.x * blockDim.x + threadIdx.x;
    if (i < n) { deg[i] = 1; cursor[i] = 0; }   // deg starts at 1: self loop
}

__global__ void count_kernel(const int* __restrict__ dst, int* __restrict__ deg, int E) {
    int i = blockIdx.x * blockDim.x + threadIdx.x;
    if (i < E) atomicAdd(&deg[dst[i]], 1);
}

// scan of padded degrees ((deg+3)&~3) — shuffle-based, 3 barriers/iter
__global__ __launch_bounds__(1024) void scan_kernel(const int* __restrict__ deg,
                                                    int* __restrict__ rowstart, int n) {
    __shared__ int wsum[16];
    __shared__ int carry_sh;
    int lane = threadIdx.x & 63, wv = threadIdx.x >> 6;
    if (threadIdx.x == 0) { carry_sh = 0; rowstart[0] = 0; }
    __syncthreads();
    for (int base = 0; base < n; base += 8192) {
        int vals[8];
        int sum = 0;
        int i0 = base + threadIdx.x * 8;
        #pragma unroll
        for (int j = 0; j < 8; ++j) {
            int i = i0 + j;
            int v = (i < n) ? ((deg[i] + 3) & ~3) : 0;
            sum += v;
            vals[j] = sum;               // local inclusive
        }
        int incl = sum;
        #pragma unroll
        for (int off = 1; off < 64; off <<= 1) {
            int t = __shfl_up(incl, off);
            if (lane >= off) incl += t;
        }
        if (lane == 63) wsum[wv] = incl;
        __syncthreads();
        if (wv == 0) {
            int s = (lane < 16) ? wsum[lane] : 0;
            #pragma unroll
            for (int off = 1; off < 16; off <<= 1) {
                int t = __shfl_up(s, off);
                if (lane >= off) s += t;
            }
            if (lane < 16) wsum[lane] = s;
        }
        __syncthreads();
        int wexcl = (wv == 0) ? 0 : wsum[wv - 1];
        int excl = carry_sh + wexcl + (incl - sum);
        #pragma unroll
        for (int j = 0; j < 8; ++j) {
            int i = i0 + j;
            if (i < n) rowstart[i + 1] = excl + vals[j];
        }
        __syncthreads();
        if (threadIdx.x == 0) carry_sh += wsum[15];
        __syncthreads();
    }
}

__global__ void scatter_kernel(const int* __restrict__ src, const int* __restrict__ dst,
                               const int* __restrict__ rowstart, int* __restrict__ cursor,
                               int* __restrict__ csr, int* __restrict__ csrd, int E, int n) {
    int i = blockIdx.x * blockDim.x + threadIdx.x;
    if (i >= E + n) return;
    int s, d;
    if (i < E) { s = src[i]; d = dst[i]; }
    else       { s = d = i - E; }          // self loop
    int p = atomicAdd(&cursor[d], 1);
    int slot = rowstart[d] + p;
    csr[slot] = s;
    csrd[slot] = d;
}

// ---------------- bf16 conversions / splits ----------------

__global__ void tobf_kernel(const float* __restrict__ A, short* __restrict__ Ah, int n4) {
    int i = blockIdx.x * blockDim.x + threadIdx.x;
    if (i >= n4) return;
    float4 v = ((const float4*)A)[i];
    s4v hv = {f2bf(v.x), f2bf(v.y), f2bf(v.z), f2bf(v.w)};
    ((s4v*)Ah)[i] = hv;
}

// B[K][Nc] fp32 -> Bt[n][k] bf16 hi/lo (k-contiguous for MFMA B-fragments)
__global__ void split_bt_kernel(const float* __restrict__ B, short* __restrict__ Bh,
                                short* __restrict__ Bl, int K, int Nc, int kshift) {
    int idx = blockIdx.x * blockDim.x + threadIdx.x;
    if (idx >= Nc * K) return;
    int n = idx >> kshift;          // K is a power of two (128/256)
    int k = idx & (K - 1);
    float v = B[(size_t)k * Nc + n];
    short h, l; split2(v, h, l);
    Bh[idx] = h;
    Bl[idx] = l;
}

// fold alphas into extra B-columns: col Nfeat+j (j<8: a_s head j, j>=8: a_d)
__global__ void fold_alpha8_kernel(const float* __restrict__ W,
                                   const float* __restrict__ a_s, const float* __restrict__ a_d,
                                   short* __restrict__ Bth, short* __restrict__ Btl,
                                   int K, int Nfeat) {
    int idx = blockIdx.x * blockDim.x + threadIdx.x;
    if (idx >= K * 16) return;
    int j = idx / K, k = idx % K;
    int h = j & 7;
    const float* av = ((j < 8) ? a_s : a_d) + h * 32;
    const float* wp = W + (size_t)k * 256 + h * 32;
    float s = 0.f;
    #pragma unroll
    for (int c = 0; c < 32; ++c) s += wp[c] * av[c];
    short hi, lo; split2(s, hi, lo);
    size_t off = (size_t)(Nfeat + j) * K + k;
    Bth[off] = hi; Btl[off] = lo;
}

// task version: 4 tasks, PADDED segments over 224 channels, K=256.
// segment starts {0,12,44,104}, padded lengths {12,32,60,120} (pads hold
// zero W and zero alpha -> contribute 0).
__global__ void fold_alpha4_kernel(const float* __restrict__ Wcat,
                                   const float* __restrict__ ascat, const float* __restrict__ adcat,
                                   short* __restrict__ Bth, short* __restrict__ Btl) {
    int idx = blockIdx.x * blockDim.x + threadIdx.x;
    if (idx >= 256 * 8) return;
    int j = idx >> 8, k = idx & 255;
    const int CO[4] = {0, 12, 44, 104};
    const int CL[4] = {12, 32, 60, 120};
    int t = j & 3;
    const float* av = ((j < 4) ? ascat : adcat) + CO[t];
    const float* wp = Wcat + (size_t)k * 224 + CO[t];
    float s = 0.f;
    for (int c = 0; c < CL[t]; ++c) s += wp[c] * av[c];
    short hi, lo; split2(s, hi, lo);
    size_t off = (size_t)(224 + j) * 256 + k;
    Bth[off] = hi; Btl[off] = lo;
}

// ---------------- bf16 MFMA GEMM + fused alpha output ----------------------

#define MB 128
#define NB 64
#define KS 32

__global__ __launch_bounds__(256) void gemm_mfma_kernel(
        const short* __restrict__ Ah_g,
        const short* __restrict__ Bth_g, const short* __restrict__ Btl_g,
        short* __restrict__ Cb, int cb_stride,
        float* __restrict__ als, float* __restrict__ ald, int nsplit,
        int M, int K, int Nfeat, int NcExt) {
    __shared__ __align__(16) short Ah[MB][40];
    __shared__ __align__(16) short Bh[NB][40];
    __shared__ __align__(16) short Bl[NB][40];

    int t = threadIdx.x;
    int lane = t & 63, w = t >> 6;
    int quad = lane >> 4, l16 = lane & 15;
    int row0 = blockIdx.y * MB, col0 = blockIdx.x * NB;

    f4v acc[2][4];
    #pragma unroll
    for (int mt = 0; mt < 2; ++mt)
        #pragma unroll
        for (int nt = 0; nt < 4; ++nt)
            acc[mt][nt] = (f4v){0.f, 0.f, 0.f, 0.f};

    for (int k0 = 0; k0 < K; k0 += KS) {
        __syncthreads();
        #pragma unroll
        for (int i = 0; i < 2; ++i) {
            int u = i * 256 + t;
            int r = u >> 2, kk = (u & 3) * 8;
            int gr = row0 + r;
            s8v vh = {0, 0, 0, 0, 0, 0, 0, 0};
            if (gr < M) vh = *(const s8v*)(Ah_g + (size_t)gr * K + k0 + kk);
            *(s8v*)&Ah[r][kk] = vh;
        }
        {
            int n = t >> 2, kk = (t & 3) * 8;
            int gc = col0 + n;
            s8v vh = {0, 0, 0, 0, 0, 0, 0, 0};
            s8v vl = {0, 0, 0, 0, 0, 0, 0, 0};
            if (gc < NcExt) {
                vh = *(const s8v*)(Bth_g + (size_t)gc * K + k0 + kk);
                vl = *(const s8v*)(Btl_g + (size_t)gc * K + k0 + kk);
            }
            *(s8v*)&Bh[n][kk] = vh;
            *(s8v*)&Bl[n][kk] = vl;
        }
        __syncthreads();

        int kb = quad * 8;
        s8v a_f[2], b_h[4], b_l[4];
        #pragma unroll
        for (int mt = 0; mt < 2; ++mt) {
            int r = w * 32 + mt * 16 + l16;
            a_f[mt] = *(const s8v*)&Ah[r][kb];
        }
        #pragma unroll
        for (int nt = 0; nt < 4; ++nt) {
            int c = nt * 16 + l16;
            b_h[nt] = *(const s8v*)&Bh[c][kb];
            b_l[nt] = *(const s8v*)&Bl[c][kb];
        }
        #pragma unroll
        for (int mt = 0; mt < 2; ++mt)
            #pragma unroll
            for (int nt = 0; nt < 4; ++nt) {
                acc[mt][nt] = __builtin_amdgcn_mfma_f32_16x16x32_bf16(
                    a_f[mt], b_h[nt], acc[mt][nt], 0, 0, 0);
                acc[mt][nt] = __builtin_amdgcn_mfma_f32_16x16x32_bf16(
                    a_f[mt], b_l[nt], acc[mt][nt], 0, 0, 0);
            }
    }

    // epilogue: C/D layout col=lane&15, row=quad*4+reg
    #pragma unroll
    for (int mt = 0; mt < 2; ++mt) {
        #pragma unroll
        for (int nt = 0; nt < 4; ++nt) {
            int gc = col0 + nt * 16 + l16;
            if (gc >= NcExt) continue;
            #pragma unroll
            for (int r = 0; r < 4; ++r) {
                int gr = row0 + w * 32 + mt * 16 + quad * 4 + r;
                if (gr >= M) continue;
                float v = acc[mt][nt][r];
                if (gc < Nfeat) {
                    Cb[(size_t)gr * cb_stride + gc] = f2bf(v);
                } else {
                    int j = gc - Nfeat;
                    if (j < nsplit)            als[(size_t)gr * nsplit + j] = v;
                    else if (j < 2 * nsplit)   ald[(size_t)gr * nsplit + (j - nsplit)] = v;
                }
            }
        }
    }
}

// ---------------- edge weights, 8 heads (unnormalized softmax) -------------
// TRANSPOSED output: ewT[h*M4 + slot]. pad slots (s<0) get zero weights.

__global__ void ew8_kernel(const float* __restrict__ als, const float* __restrict__ ald,
                           const int* __restrict__ csr, const int* __restrict__ csrd,
                           float* __restrict__ ewT, int M4) {
    int i = blockIdx.x * blockDim.x + threadIdx.x;
    if (i >= M4) return;
    int s = csr[i], d = csrd[i];
    if (s < 0) {
        #pragma unroll
        for (int h = 0; h < 8; ++h) ewT[(size_t)h * M4 + i] = 0.f;
        return;
    }
    const float4* ap = (const float4*)(als + (size_t)s * 8);
    const float4* dp = (const float4*)(ald + (size_t)d * 8);
    float4 a0 = ap[0], a1 = ap[1];
    float4 d0 = dp[0], d1 = dp[1];
    float v[8] = {a0.x + d0.x, a0.y + d0.y, a0.z + d0.z, a0.w + d0.w,
                  a1.x + d1.x, a1.y + d1.y, a1.z + d1.z, a1.w + d1.w};
    #pragma unroll
    for (int h = 0; h < 8; ++h) {
        float x = v[h];
        x = (x > 0.f) ? x : NEG_SLOPE * x;
        ewT[(size_t)h * M4 + i] = __expf(x);
    }
}

// ---------------- GAT gather (8 heads x 32 ch), one wave per dst -----------
// Per-wave CSR index preload + readlane extraction; plane-transposed ew.

__global__ __launch_bounds__(256) void gat_gather_kernel(
        const short* __restrict__ hb, const float* __restrict__ ewT,
        const int* __restrict__ rowstart, const int* __restrict__ csr,
        const float* __restrict__ bias, short* __restrict__ oh, int n, int elu,
        int M4) {
    int wid  = blockIdx.x * 4 + (threadIdx.x >> 6);
    int lane = threadIdx.x & 63;
    if (wid >= n) return;
    int row = rowstart[wid];
    int pdeg = rowstart[wid + 1] - row;
    int hp = lane >> 3;
    int ch = lane * 4;
    const int* cp = csr + row;
    const float* wp = ewT + (size_t)hp * M4 + row;

    float4 acc = {0.f, 0.f, 0.f, 0.f};
    float wsum = 0.f;
    for (int base = 0; base < pdeg; base += 64) {
        int cnt = min(pdeg - base, 64);
        int idxv = -1;
        if (lane < cnt) idxv = cp[base + lane];
        const float* wpb = wp + base;
        int e = 0;
        for (; e + 8 <= cnt; e += 8) {
            int si[8];
            #pragma unroll
            for (int i = 0; i < 8; ++i) si[i] = rl_at(idxv, e + i);
            float4 wa = *(const float4*)(wpb + e);
            float4 wb = *(const float4*)(wpb + e + 4);
            s4v hv[8];
            #pragma unroll
            for (int i = 0; i < 8; ++i)
                hv[i] = *(const s4v*)(hb + (size_t)si[i] * 256 + ch);
            float wv[8] = {wa.x, wa.y, wa.z, wa.w, wb.x, wb.y, wb.z, wb.w};
            #pragma unroll
            for (int i = 0; i < 8; ++i) {
                float4 h = bf4_to_f4(hv[i]);
                acc.x += wv[i] * h.x; acc.y += wv[i] * h.y;
                acc.z += wv[i] * h.z; acc.w += wv[i] * h.w;
                wsum += wv[i];
            }
        }
        for (; e < cnt; e += 4) {        // runs at most once (rows padded x4)
            int si[4];
            #pragma unroll
            for (int i = 0; i < 4; ++i) si[i] = rl_at(idxv, e + i);
            float4 wa = *(const float4*)(wpb + e);
            s4v hv[4];
            #pragma unroll
            for (int i = 0; i < 4; ++i)
                hv[i] = *(const s4v*)(hb + (size_t)si[i] * 256 + ch);
            float wv[4] = {wa.x, wa.y, wa.z, wa.w};
            #pragma unroll
            for (int i = 0; i < 4; ++i) {
                float4 h = bf4_to_f4(hv[i]);
                acc.x += wv[i] * h.x; acc.y += wv[i] * h.y;
                acc.z += wv[i] * h.z; acc.w += wv[i] * h.w;
                wsum += wv[i];
            }
        }
    }
    float inv = 1.f / (wsum + 1e-16f);
    float4 b4 = *(const float4*)(bias + ch);
    float v[4] = {acc.x * inv + b4.x, acc.y * inv + b4.y,
                  acc.z * inv + b4.z, acc.w * inv + b4.w};
    if (elu) {
        #pragma unroll
        for (int j = 0; j < 4; ++j)
            v[j] = (v[j] > 0.f) ? v[j] : __expf(v[j]) - 1.f;
    }
    s4v hvo = {f2bf(v[0]), f2bf(v[1]), f2bf(v[2]), f2bf(v[3])};
    *(s4v*)(oh + (size_t)wid * 256 + ch) = hvo;
}

// ---------------- task-head packing (Wcat, bcat, ascat, adcat) -------------
// PADDED 224-channel layout: segments at {0,12,44,104}, pad cols 42,43 zero.

__global__ void pack_w_kernel(const float* __restrict__ wTL, const float* __restrict__ wYL,
                              const float* __restrict__ wTS, const float* __restrict__ wTZ,
                              const float* __restrict__ bTL, const float* __restrict__ bYL,
                              const float* __restrict__ bTS, const float* __restrict__ bTZ,
                              const float* __restrict__ asTL, const float* __restrict__ asYL,
                              const float* __restrict__ asTS, const float* __restrict__ asTZ,
                              const float* __restrict__ adTL, const float* __restrict__ adYL,
                              const float* __restrict__ adTS, const float* __restrict__ adTZ,
                              float* __restrict__ Wcat, float* __restrict__ bcat,
                              float* __restrict__ ascat, float* __restrict__ adcat) {
    int idx = blockIdx.x * blockDim.x + threadIdx.x;
    if (idx < 256 * 224) {
        int r = idx / 224, c = idx % 224;
        float v = 0.f;
        if (c < 12)       v = wTL[r * 12 + c];
        else if (c < 42)  v = wYL[r * 30 + (c - 12)];
        else if (c < 44)  v = 0.f;
        else if (c < 104) v = wTS[r * 60 + (c - 44)];
        else              v = wTZ[r * 120 + (c - 104)];
        Wcat[idx] = v;
    }
    if (idx < 224) {
        float b = 0.f, as_ = 0.f, ad_ = 0.f;
        if (idx < 12)       { b = bTL[idx];       as_ = asTL[idx];       ad_ = adTL[idx]; }
        else if (idx < 42)  { b = bYL[idx - 12];  as_ = asYL[idx - 12];  ad_ = adYL[idx - 12]; }
        else if (idx < 44)  { }
        else if (idx < 104) { b = bTS[idx - 44];  as_ = asTS[idx - 44];  ad_ = adTS[idx - 44]; }
        else                { b = bTZ[idx - 104]; as_ = asTZ[idx - 104]; ad_ = adTZ[idx - 104]; }
        bcat[idx]  = b;
        ascat[idx] = as_;
        adcat[idx] = ad_;
    }
}

// ---------------- edge weights, 4 tasks (transposed planes) ----------------

__global__ void ew4_kernel(const float* __restrict__ ast, const float* __restrict__ adt,
                           const int* __restrict__ csr, const int* __restrict__ csrd,
                           float* __restrict__ ewT, int M4) {
    int i = blockIdx.x * blockDim.x + threadIdx.x;
    if (i >= M4) return;
    int s = csr[i], d = csrd[i];
    if (s < 0) {
        #pragma unroll
        for (int t = 0; t < 4; ++t) ewT[(size_t)t * M4 + i] = 0.f;
        return;
    }
    float4 a = *(const float4*)(ast + (size_t)s * 4);
    float4 b = *(const float4*)(adt + (size_t)d * 4);
    float v[4] = {a.x + b.x, a.y + b.y, a.z + b.z, a.w + b.w};
    #pragma unroll
    for (int t = 0; t < 4; ++t) {
        float x = v[t];
        x = (x > 0.f) ? x : NEG_SLOPE * x;
        ewT[(size_t)t * M4 + i] = __expf(x);
    }
}

// ---------------- 4-task gather + fused log_softmax (register-only) --------
// Padded 224-ch layout: lane*4 channels lie in exactly ONE task segment.

__device__ __forceinline__ float sel4(int t, float v0, float v1, float v2, float v3) {
    return (t == 0) ? v0 : (t == 1) ? v1 : (t == 2) ? v2 : v3;
}

__global__ __launch_bounds__(256) void task_gather_ls_kernel(
        const short* __restrict__ htb, const float* __restrict__ ewT,
        const int* __restrict__ rowstart, const int* __restrict__ csr,
        const float* __restrict__ bcat, float* __restrict__ out, int n, int M4) {
    int wid  = blockIdx.x * 4 + (threadIdx.x >> 6);
    int lane = threadIdx.x & 63;
    if (wid >= n) return;
    int row = rowstart[wid];
    int pdeg = rowstart[wid + 1] - row;
    int ch0 = lane * 4;
    int t = (lane < 3) ? 0 : (lane < 11) ? 1 : (lane < 26) ? 2 : 3;
    int COp = (t == 0) ? 0 : (t == 1) ? 12 : (t == 2) ? 44 : 104;   // padded start
    int COr = (t == 0) ? 0 : (t == 1) ? 12 : (t == 2) ? 42 : 102;   // real out offset
    int CLr = (t == 0) ? 12 : (t == 1) ? 30 : (t == 2) ? 60 : 120;  // real length
    bool valj[4];
    #pragma unroll
    for (int j = 0; j < 4; ++j)
        valj[j] = (unsigned)(ch0 + j - COp) < (unsigned)CLr;

    const int* cp = csr + row;
    const float* wp = ewT + (size_t)t * M4 + row;

    float acc[4] = {0.f, 0.f, 0.f, 0.f};
    float ws = 0.f;
    for (int base = 0; base < pdeg; base += 64) {
        int cnt = min(pdeg - base, 64);
        int idxv = -1;
        if (lane < cnt) idxv = cp[base + lane];
        const float* wpb = wp + base;
        int e = 0;
        for (; e + 8 <= cnt; e += 8) {
            int si[8];
            #pragma unroll
            for (int i = 0; i < 8; ++i) si[i] = rl_at(idxv, e + i);
            float4 wa = *(const float4*)(wpb + e);
            float4 wb = *(const float4*)(wpb + e + 4);
            s4v hv[8];
            #pragma unroll
            for (int i = 0; i < 8; ++i)
                hv[i] = *(const s4v*)(htb + (size_t)si[i] * 224 + ch0);
            float wv[8] = {wa.x, wa.y, wa.z, wa.w, wb.x, wb.y, wb.z, wb.w};
            #pragma unroll
            for (int i = 0; i < 8; ++i) {
                float4 h = bf4_to_f4(hv[i]);
                acc[0] += wv[i] * h.x; acc[1] += wv[i] * h.y;
                acc[2] += wv[i] * h.z; acc[3] += wv[i] * h.w;
                ws += wv[i];
            }
        }
        for (; e < cnt; e += 4) {        // runs at most once (rows padded x4)
            int si[4];
            #pragma unroll
            for (int i = 0; i < 4; ++i) si[i] = rl_at(idxv, e + i);
            float4 wa = *(const float4*)(wpb + e);
            s4v hv[4];
            #pragma unroll
            for (int i = 0; i < 4; ++i)
                hv[i] = *(const s4v*)(htb + (size_t)si[i] * 224 + ch0);
            float wv[4] = {wa.x, wa.y, wa.z, wa.w};
            #pragma unroll
            for (int i = 0; i < 4; ++i) {
                float4 h = bf4_to_f4(hv[i]);
                acc[0] += wv[i] * h.x; acc[1] += wv[i] * h.y;
                acc[2] += wv[i] * h.z; acc[3] += wv[i] * h.w;
                ws += wv[i];
            }
        }
    }
    float inv = 1.f / (ws + 1e-16f);

    // normalized logits; per-lane max for its (single) task
    float vout[4];
    float m = -1e30f;
    #pragma unroll
    for (int j = 0; j < 4; ++j) {
        float v = 0.f;
        if (valj[j]) { v = acc[j] * inv + bcat[ch0 + j]; m = fmaxf(m, v); }
        vout[j] = v;
    }
    float m0 = (t == 0) ? m : -1e30f;
    float m1 = (t == 1) ? m : -1e30f;
    float m2 = (t == 2) ? m : -1e30f;
    float m3 = (t == 3) ? m : -1e30f;
    #pragma unroll
    for (int off = 1; off < 64; off <<= 1) {
        m0 = fmaxf(m0, __shfl_xor(m0, off));
        m1 = fmaxf(m1, __shfl_xor(m1, off));
        m2 = fmaxf(m2, __shfl_xor(m2, off));
        m3 = fmaxf(m3, __shfl_xor(m3, off));
    }
    float mt = sel4(t, m0, m1, m2, m3);
    float sacc = 0.f;
    #pragma unroll
    for (int j = 0; j < 4; ++j)
        if (valj[j]) sacc += __expf(vout[j] - mt);
    float s0 = (t == 0) ? sacc : 0.f;
    float s1 = (t == 1) ? sacc : 0.f;
    float s2 = (t == 2) ? sacc : 0.f;
    float s3 = (t == 3) ? sacc : 0.f;
    #pragma unroll
    for (int off = 1; off < 64; off <<= 1) {
        s0 += __shfl_xor(s0, off);
        s1 += __shfl_xor(s1, off);
        s2 += __shfl_xor(s2, off);
        s3 += __shfl_xor(s3, off);
    }
    float st = sel4(t, s0, s1, s2, s3);
    float lse = mt + __logf(st);
    #pragma unroll
    for (int j = 0; j < 4; ++j)
        if (valj[j])
            out[(size_t)COr * n + (size_t)wid * CLr + (ch0 + j - COp)] = vout[j] - lse;
}

// ---------------- launcher ----------------

extern "C" void kernel_launch(void* const* d_in, const int* in_sizes, int n_in,
                              void* d_out, int out_size, void* d_ws, size_t ws_size,
                              hipStream_t stream) {
    const float* x   = (const float*)d_in[0];
    const int*   ei  = (const int*)d_in[1];
    const float* W1  = (const float*)d_in[2];
    const float* a1s = (const float*)d_in[3];
    const float* a1d = (const float*)d_in[4];
    const float* b1  = (const float*)d_in[5];
    const float* W2  = (const float*)d_in[6];
    const float* a2s = (const float*)d_in[7];
    const float* a2d = (const float*)d_in[8];
    const float* b2  = (const float*)d_in[9];
    const float* W_TL = (const float*)d_in[10]; const float* as_TL = (const float*)d_in[11];
    const float* ad_TL = (const float*)d_in[12]; const float* b_TL = (const float*)d_in[13];
    const float* W_YL = (const float*)d_in[14]; const float* as_YL = (const float*)d_in[15];
    const float* ad_YL = (const float*)d_in[16]; const float* b_YL = (const float*)d_in[17];
    const float* W_TS = (const float*)d_in[18]; const float* as_TS = (const float*)d_in[19];
    const float* ad_TS = (const float*)d_in[20]; const float* b_TS = (const float*)d_in[21];
    const float* W_TZ = (const float*)d_in[22]; const float* as_TZ = (const float*)d_in[23];
    const float* ad_TZ = (const float*)d_in[24]; const float* b_TZ = (const float*)d_in[25];

    const int N = in_sizes[0] / 128;
    const int E = in_sizes[1] / 2;
    const int* e_src = ei;
    const int* e_dst = ei + E;
    const int M4 = E + 4 * N;              // padded CSR slot bound (rows x4)

    float* ws = (float*)d_ws;
    float* B1   = ws;
    float* B2   = B1 + (size_t)N * 256;
    float* B3   = B2 + (size_t)N * 256;
    float* as1  = B3 + (size_t)N * 256;    // N*8
    float* ad1  = as1 + (size_t)N * 8;
    float* as2  = ad1 + (size_t)N * 8;
    float* ad2  = as2 + (size_t)N * 8;
    float* ast  = ad2 + (size_t)N * 8;     // N*4
    float* adt  = ast + (size_t)N * 4;
    float* Wcat = adt + (size_t)N * 4;     // 256*224 (padded task layout)
    float* bcat = Wcat + 256 * 224;        // 224
    float* ascat = bcat + 224;
    float* adcat = ascat + 224;
    int* deg      = (int*)(adcat + 224);   // N
    int* rowstart = deg + N;               // N+1 (cap N+4, keeps csr 16B-aligned)
    int* cursor   = rowstart + (N + 4);    // N
    int* csr      = cursor + N;            // M4 (16B-aligned)
    int* csrd     = csr + M4;              // M4
    uintptr_t wsp = (uintptr_t)(csrd + M4);
    wsp = (wsp + 15) & ~(uintptr_t)15;
    short* W1h = (short*)wsp;              // 272*128 (256 feat + 16 alpha)
    short* W1l = W1h + 272 * 128;
    short* W2h = W1l + 272 * 128;          // 272*256
    short* W2l = W2h + 272 * 256;
    short* Wth = W2l + 272 * 256;          // 232*256 (224 feat + 8 alpha)
    short* Wtl = Wth + 232 * 256;
    // overlays
    short* Xh  = (short*)B1;               // N*128
    short* Sh  = (short*)B1;               // N*256
    short* Th  = (short*)B1;               // N*256
    short* h1b = (short*)B2;               // stride 256
    short* h2b = (short*)B2;               // stride 256
    short* htb = (short*)B2;               // stride 224
    float* ew1 = B3;                       // 8 planes x M4
    float* ew2 = B3;
    float* ewt = B3;                       // 4 planes x M4

    float* out = (float*)d_out;

    const int B = 256;
    // --- CSR build (padded rows) ---
    init_kernel<<<(N + B - 1) / B, B, 0, stream>>>(deg, cursor, N);
    count_kernel<<<(E + B - 1) / B, B, 0, stream>>>(e_dst, deg, E);
    scan_kernel<<<1, 1024, 0, stream>>>(deg, rowstart, N);
    hipMemsetAsync(csr, 0xFF, (size_t)2 * M4 * sizeof(int), stream);   // csr+csrd = -1
    scatter_kernel<<<(E + N + B - 1) / B, B, 0, stream>>>(e_src, e_dst, rowstart, cursor, csr, csrd, E, N);
    // --- pack + split + fold weights ---
    pack_w_kernel<<<(256 * 224 + B - 1) / B, B, 0, stream>>>(W_TL, W_YL, W_TS, W_TZ,
        b_TL, b_YL, b_TS, b_TZ, as_TL, as_YL, as_TS, as_TZ, ad_TL, ad_YL, ad_TS, ad_TZ,
        Wcat, bcat, ascat, adcat);
    split_bt_kernel<<<(256 * 128 + B - 1) / B, B, 0, stream>>>(W1, W1h, W1l, 128, 256, 7);
    split_bt_kernel<<<(256 * 256 + B - 1) / B, B, 0, stream>>>(W2, W2h, W2l, 256, 256, 8);
    split_bt_kernel<<<(224 * 256 + B - 1) / B, B, 0, stream>>>(Wcat, Wth, Wtl, 256, 224, 8);
    fold_alpha8_kernel<<<(128 * 16 + B - 1) / B, B, 0, stream>>>(W1, a1s, a1d, W1h, W1l, 128, 256);
    fold_alpha8_kernel<<<(256 * 16 + B - 1) / B, B, 0, stream>>>(W2, a2s, a2d, W2h, W2l, 256, 256);
    fold_alpha4_kernel<<<(256 * 8 + B - 1) / B, B, 0, stream>>>(Wcat, ascat, adcat, Wth, Wtl);
    // --- conv1: GEMM emits h1b bf16 + als1/ald1 directly ---
    tobf_kernel<<<((N * 128 / 4) + B - 1) / B, B, 0, stream>>>(x, Xh, N * 128 / 4);
    {
        dim3 g((272 + NB - 1) / NB, (N + MB - 1) / MB);
        gemm_mfma_kernel<<<g, 256, 0, stream>>>(Xh, W1h, W1l, h1b, 256,
                                                as1, ad1, 8, N, 128, 256, 272);
    }
    ew8_kernel<<<(M4 + B - 1) / B, B, 0, stream>>>(as1, ad1, csr, csrd, ew1, M4);
    gat_gather_kernel<<<(N + 3) / 4, 256, 0, stream>>>(h1b, ew1, rowstart, csr, b1, Sh, N, 1, M4);
    // --- conv2 ---
    {
        dim3 g((272 + NB - 1) / NB, (N + MB - 1) / MB);
        gemm_mfma_kernel<<<g, 256, 0, stream>>>(Sh, W2h, W2l, h2b, 256,
                                                as2, ad2, 8, N, 256, 256, 272);
    }
    ew8_kernel<<<(M4 + B - 1) / B, B, 0, stream>>>(as2, ad2, csr, csrd, ew2, M4);
    gat_gather_kernel<<<(N + 3) / 4, 256, 0, stream>>>(h2b, ew2, rowstart, csr, b2, Th, N, 0, M4);
    // --- task heads: GEMM emits htb bf16 (stride 224, padded) + ast/adt ---
    {
        dim3 g((232 + NB - 1) / NB, (N + MB - 1) / MB);
        gemm_mfma_kernel<<<g, 256, 0, stream>>>(Th, Wth, Wtl, htb, 224,
                                                ast, adt, 4, N, 256, 224, 232);
    }
    ew4_kernel<<<(M4 + B - 1) / B, B, 0, stream>>>(ast, adt, csr, csrd, ewt, M4);
    task_gather_ls_kernel<<<(N + 3) / 4, 256, 0, stream>>>(htb, ewt, rowstart, csr, bcat, out, N, M4);
}

// Round 3
// 596.483 us; speedup vs baseline: 1.0584x; 1.0363x over previous
//
#include <hip/hip_runtime.h>
#include <math.h>

// ---------------------------------------------------------------------------
// MultiTaskGAT: 2x GATConv(8 heads x 32ch, concat) + 4 task heads (1 head)
// N=50000 nodes, E=800000 edges (+N self loops), F_IN=128, DH=256.
//
// R4: GEMMs -> bf16 MFMA hi/lo split.
// R6: alphas folded into GEMM B-columns; log_softmax fused into task gather.
// R8: CSR rows padded to x4; shuffle-based scan kernel.
// R9: per-wave CSR index preload (1 coalesced load + v_readlane); task
//     channel layout padded to 224 (starts 0,12,44,104) so each lane owns
//     one task; 8-edge groups with loads issued ahead of consumption.
// R11: edge-weight kernels (ew8/ew4) FUSED into the gathers:
//     w = exp(leaky(als[s]+ald[d])) computed inline (s is SGPR -> als load
//     is one 32B wave-request into an L2-resident 1.6MB table; d == wid).
//     Deletes 3 dispatches, the csrd array (memset+write+read), and the
//     ~80MB ew round-trip. Task gather lanes 56-63 clamp ch0 -> 0 (their
//     old loads fetched a useless extra cacheline per edge).
// ---------------------------------------------------------------------------

#define NEG_SLOPE 0.2f

typedef short s8v __attribute__((ext_vector_type(8)));
typedef short s4v __attribute__((ext_vector_type(4)));
typedef float f4v __attribute__((ext_vector_type(4)));

__device__ __forceinline__ short f2bf(float x) {
    unsigned u = __float_as_uint(x);
    u += 0x7fffu + ((u >> 16) & 1u);
    return (short)(u >> 16);
}
__device__ __forceinline__ float bf2f(short b) {
    return __uint_as_float(((unsigned)(unsigned short)b) << 16);
}
__device__ __forceinline__ void split2(float x, short& h, short& l) {
    h = f2bf(x);
    l = f2bf(x - bf2f(h));
}
__device__ __forceinline__ float4 bf4_to_f4(s4v v) {
    return make_float4(bf2f(v[0]), bf2f(v[1]), bf2f(v[2]), bf2f(v[3]));
}
// leaky_relu(x) == max(x, 0.2x) for slope<1
__device__ __forceinline__ float leaky(float x) {
    return fmaxf(x, NEG_SLOPE * x);
}

// ---------------- CSR build ----------------

__global__ void init_kernel(int* __restrict__ deg, int* __restrict__ cursor, int n) {
    int i = blockIdx.x * blockDim.x + threadIdx.x;
    if (i < n) { deg[i] = 1; cursor[i] = 0; }   // deg starts at 1: self loop
}

__global__ void count_kernel(const int* __restrict__ dst, int* __restrict__ deg, int E) {
    int i = blockIdx.x * blockDim.x + threadIdx.x;
    if (i < E) atomicAdd(&deg[dst[i]], 1);
}

// scan of padded degrees ((deg+3)&~3) — shuffle-based, 3 barriers/iter
__global__ __launch_bounds__(1024) void scan_kernel(const int* __restrict__ deg,
                                                    int* __restrict__ rowstart, int n) {
    __shared__ int wsum[16];
    __shared__ int carry_sh;
    int lane = threadIdx.x & 63, wv = threadIdx.x >> 6;
    if (threadIdx.x == 0) { carry_sh = 0; rowstart[0] = 0; }
    __syncthreads();
    for (int base = 0; base < n; base += 8192) {
        int vals[8];
        int sum = 0;
        int i0 = base + threadIdx.x * 8;
        #pragma unroll
        for (int j = 0; j < 8; ++j) {
            int i = i0 + j;
            int v = (i < n) ? ((deg[i] + 3) & ~3) : 0;
            sum += v;
            vals[j] = sum;               // local inclusive
        }
        int incl = sum;
        #pragma unroll
        for (int off = 1; off < 64; off <<= 1) {
            int t = __shfl_up(incl, off);
            if (lane >= off) incl += t;
        }
        if (lane == 63) wsum[wv] = incl;
        __syncthreads();
        if (wv == 0) {
            int s = (lane < 16) ? wsum[lane] : 0;
            #pragma unroll
            for (int off = 1; off < 16; off <<= 1) {
                int t = __shfl_up(s, off);
                if (lane >= off) s += t;
            }
            if (lane < 16) wsum[lane] = s;
        }
        __syncthreads();
        int wexcl = (wv == 0) ? 0 : wsum[wv - 1];
        int excl = carry_sh + wexcl + (incl - sum);
        #pragma unroll
        for (int j = 0; j < 8; ++j) {
            int i = i0 + j;
            if (i < n) rowstart[i + 1] = excl + vals[j];
        }
        __syncthreads();
        if (threadIdx.x == 0) carry_sh += wsum[15];
        __syncthreads();
    }
}

__global__ void scatter_kernel(const int* __restrict__ src, const int* __restrict__ dst,
                               const int* __restrict__ rowstart, int* __restrict__ cursor,
                               int* __restrict__ csr, int E, int n) {
    int i = blockIdx.x * blockDim.x + threadIdx.x;
    if (i >= E + n) return;
    int s, d;
    if (i < E) { s = src[i]; d = dst[i]; }
    else       { s = d = i - E; }          // self loop
    int p = atomicAdd(&cursor[d], 1);
    csr[rowstart[d] + p] = s;
}

// ---------------- bf16 conversions / splits ----------------

__global__ void tobf_kernel(const float* __restrict__ A, short* __restrict__ Ah, int n4) {
    int i = blockIdx.x * blockDim.x + threadIdx.x;
    if (i >= n4) return;
    float4 v = ((const float4*)A)[i];
    s4v hv = {f2bf(v.x), f2bf(v.y), f2bf(v.z), f2bf(v.w)};
    ((s4v*)Ah)[i] = hv;
}

// B[K][Nc] fp32 -> Bt[n][k] bf16 hi/lo (k-contiguous for MFMA B-fragments)
__global__ void split_bt_kernel(const float* __restrict__ B, short* __restrict__ Bh,
                                short* __restrict__ Bl, int K, int Nc, int kshift) {
    int idx = blockIdx.x * blockDim.x + threadIdx.x;
    if (idx >= Nc * K) return;
    int n = idx >> kshift;          // K is a power of two (128/256)
    int k = idx & (K - 1);
    float v = B[(size_t)k * Nc + n];
    short h, l; split2(v, h, l);
    Bh[idx] = h;
    Bl[idx] = l;
}

// fold alphas into extra B-columns: col Nfeat+j (j<8: a_s head j, j>=8: a_d)
__global__ void fold_alpha8_kernel(const float* __restrict__ W,
                                   const float* __restrict__ a_s, const float* __restrict__ a_d,
                                   short* __restrict__ Bth, short* __restrict__ Btl,
                                   int K, int Nfeat) {
    int idx = blockIdx.x * blockDim.x + threadIdx.x;
    if (idx >= K * 16) return;
    int j = idx / K, k = idx % K;
    int h = j & 7;
    const float* av = ((j < 8) ? a_s : a_d) + h * 32;
    const float* wp = W + (size_t)k * 256 + h * 32;
    float s = 0.f;
    #pragma unroll
    for (int c = 0; c < 32; ++c) s += wp[c] * av[c];
    short hi, lo; split2(s, hi, lo);
    size_t off = (size_t)(Nfeat + j) * K + k;
    Bth[off] = hi; Btl[off] = lo;
}

// task version: 4 tasks, PADDED segments over 224 channels, K=256.
// segment starts {0,12,44,104}, padded lengths {12,32,60,120} (pads hold
// zero W and zero alpha -> contribute 0).
__global__ void fold_alpha4_kernel(const float* __restrict__ Wcat,
                                   const float* __restrict__ ascat, const float* __restrict__ adcat,
                                   short* __restrict__ Bth, short* __restrict__ Btl) {
    int idx = blockIdx.x * blockDim.x + threadIdx.x;
    if (idx >= 256 * 8) return;
    int j = idx >> 8, k = idx & 255;
    const int CO[4] = {0, 12, 44, 104};
    const int CL[4] = {12, 32, 60, 120};
    int t = j & 3;
    const float* av = ((j < 4) ? ascat : adcat) + CO[t];
    const float* wp = Wcat + (size_t)k * 224 + CO[t];
    float s = 0.f;
    for (int c = 0; c < CL[t]; ++c) s += wp[c] * av[c];
    short hi, lo; split2(s, hi, lo);
    size_t off = (size_t)(224 + j) * 256 + k;
    Bth[off] = hi; Btl[off] = lo;
}

// ---------------- bf16 MFMA GEMM + fused alpha output ----------------------

#define MB 128
#define NB 64
#define KS 32

__global__ __launch_bounds__(256) void gemm_mfma_kernel(
        const short* __restrict__ Ah_g,
        const short* __restrict__ Bth_g, const short* __restrict__ Btl_g,
        short* __restrict__ Cb, int cb_stride,
        float* __restrict__ als, float* __restrict__ ald, int nsplit,
        int M, int K, int Nfeat, int NcExt) {
    __shared__ __align__(16) short Ah[MB][40];
    __shared__ __align__(16) short Bh[NB][40];
    __shared__ __align__(16) short Bl[NB][40];

    int t = threadIdx.x;
    int lane = t & 63, w = t >> 6;
    int quad = lane >> 4, l16 = lane & 15;
    int row0 = blockIdx.y * MB, col0 = blockIdx.x * NB;

    f4v acc[2][4];
    #pragma unroll
    for (int mt = 0; mt < 2; ++mt)
        #pragma unroll
        for (int nt = 0; nt < 4; ++nt)
            acc[mt][nt] = (f4v){0.f, 0.f, 0.f, 0.f};

    for (int k0 = 0; k0 < K; k0 += KS) {
        __syncthreads();
        #pragma unroll
        for (int i = 0; i < 2; ++i) {
            int u = i * 256 + t;
            int r = u >> 2, kk = (u & 3) * 8;
            int gr = row0 + r;
            s8v vh = {0, 0, 0, 0, 0, 0, 0, 0};
            if (gr < M) vh = *(const s8v*)(Ah_g + (size_t)gr * K + k0 + kk);
            *(s8v*)&Ah[r][kk] = vh;
        }
        {
            int n = t >> 2, kk = (t & 3) * 8;
            int gc = col0 + n;
            s8v vh = {0, 0, 0, 0, 0, 0, 0, 0};
            s8v vl = {0, 0, 0, 0, 0, 0, 0, 0};
            if (gc < NcExt) {
                vh = *(const s8v*)(Bth_g + (size_t)gc * K + k0 + kk);
                vl = *(const s8v*)(Btl_g + (size_t)gc * K + k0 + kk);
            }
            *(s8v*)&Bh[n][kk] = vh;
            *(s8v*)&Bl[n][kk] = vl;
        }
        __syncthreads();

        int kb = quad * 8;
        s8v a_f[2], b_h[4], b_l[4];
        #pragma unroll
        for (int mt = 0; mt < 2; ++mt) {
            int r = w * 32 + mt * 16 + l16;
            a_f[mt] = *(const s8v*)&Ah[r][kb];
        }
        #pragma unroll
        for (int nt = 0; nt < 4; ++nt) {
            int c = nt * 16 + l16;
            b_h[nt] = *(const s8v*)&Bh[c][kb];
            b_l[nt] = *(const s8v*)&Bl[c][kb];
        }
        #pragma unroll
        for (int mt = 0; mt < 2; ++mt)
            #pragma unroll
            for (int nt = 0; nt < 4; ++nt) {
                acc[mt][nt] = __builtin_amdgcn_mfma_f32_16x16x32_bf16(
                    a_f[mt], b_h[nt], acc[mt][nt], 0, 0, 0);
                acc[mt][nt] = __builtin_amdgcn_mfma_f32_16x16x32_bf16(
                    a_f[mt], b_l[nt], acc[mt][nt], 0, 0, 0);
            }
    }

    // epilogue: C/D layout col=lane&15, row=quad*4+reg
    #pragma unroll
    for (int mt = 0; mt < 2; ++mt) {
        #pragma unroll
        for (int nt = 0; nt < 4; ++nt) {
            int gc = col0 + nt * 16 + l16;
            if (gc >= NcExt) continue;
            #pragma unroll
            for (int r = 0; r < 4; ++r) {
                int gr = row0 + w * 32 + mt * 16 + quad * 4 + r;
                if (gr >= M) continue;
                float v = acc[mt][nt][r];
                if (gc < Nfeat) {
                    Cb[(size_t)gr * cb_stride + gc] = f2bf(v);
                } else {
                    int j = gc - Nfeat;
                    if (j < nsplit)            als[(size_t)gr * nsplit + j] = v;
                    else if (j < 2 * nsplit)   ald[(size_t)gr * nsplit + (j - nsplit)] = v;
                }
            }
        }
    }
}

// ---------------- GAT gather (8 heads x 32 ch), one wave per dst -----------
// Per-wave CSR index preload + readlane extraction; edge weight computed
// inline: w = exp(leaky(als[s*8+hp] + ald[wid*8+hp])); pad slots w=0.

__global__ __launch_bounds__(256) void gat_gather_kernel(
        const short* __restrict__ hb,
        const float* __restrict__ als, const float* __restrict__ ald,
        const int* __restrict__ rowstart, const int* __restrict__ csr,
        const float* __restrict__ bias, short* __restrict__ oh, int n, int elu) {
    int wid  = blockIdx.x * 4 + (threadIdx.x >> 6);
    int lane = threadIdx.x & 63;
    if (wid >= n) return;
    int row = rowstart[wid];
    int pdeg = rowstart[wid + 1] - row;
    int hp = lane >> 3;
    int ch = lane * 4;
    const int* cp = csr + row;
    float aldd = ald[(size_t)wid * 8 + hp];

    float4 acc = {0.f, 0.f, 0.f, 0.f};
    float wsum = 0.f;
    for (int base = 0; base < pdeg; base += 64) {
        int cnt = min(pdeg - base, 64);
        int idxv = -1;
        if (lane < cnt) idxv = cp[base + lane];
        int e = 0;
        for (; e + 8 <= cnt; e += 8) {
            int raw[8], si[8];
            #pragma unroll
            for (int i = 0; i < 8; ++i) {
                raw[i] = __builtin_amdgcn_readlane(idxv, e + i);
                si[i] = raw[i] < 0 ? 0 : raw[i];
            }
            float av[8];
            #pragma unroll
            for (int i = 0; i < 8; ++i)
                av[i] = als[(size_t)si[i] * 8 + hp];
            s4v hv[8];
            #pragma unroll
            for (int i = 0; i < 8; ++i)
                hv[i] = *(const s4v*)(hb + (size_t)si[i] * 256 + ch);
            #pragma unroll
            for (int i = 0; i < 8; ++i) {
                float wgt = __expf(leaky(av[i] + aldd));
                if (raw[i] < 0) wgt = 0.f;
                float4 h = bf4_to_f4(hv[i]);
                acc.x += wgt * h.x; acc.y += wgt * h.y;
                acc.z += wgt * h.z; acc.w += wgt * h.w;
                wsum += wgt;
            }
        }
        for (; e < cnt; e += 4) {        // runs at most once (rows padded x4)
            int raw[4], si[4];
            #pragma unroll
            for (int i = 0; i < 4; ++i) {
                raw[i] = __builtin_amdgcn_readlane(idxv, e + i);
                si[i] = raw[i] < 0 ? 0 : raw[i];
            }
            float av[4];
            #pragma unroll
            for (int i = 0; i < 4; ++i)
                av[i] = als[(size_t)si[i] * 8 + hp];
            s4v hv[4];
            #pragma unroll
            for (int i = 0; i < 4; ++i)
                hv[i] = *(const s4v*)(hb + (size_t)si[i] * 256 + ch);
            #pragma unroll
            for (int i = 0; i < 4; ++i) {
                float wgt = __expf(leaky(av[i] + aldd));
                if (raw[i] < 0) wgt = 0.f;
                float4 h = bf4_to_f4(hv[i]);
                acc.x += wgt * h.x; acc.y += wgt * h.y;
                acc.z += wgt * h.z; acc.w += wgt * h.w;
                wsum += wgt;
            }
        }
    }
    float inv = 1.f / (wsum + 1e-16f);
    float4 b4 = *(const float4*)(bias + ch);
    float v[4] = {acc.x * inv + b4.x, acc.y * inv + b4.y,
                  acc.z * inv + b4.z, acc.w * inv + b4.w};
    if (elu) {
        #pragma unroll
        for (int j = 0; j < 4; ++j)
            v[j] = (v[j] > 0.f) ? v[j] : __expf(v[j]) - 1.f;
    }
    s4v hvo = {f2bf(v[0]), f2bf(v[1]), f2bf(v[2]), f2bf(v[3])};
    *(s4v*)(oh + (size_t)wid * 256 + ch) = hvo;
}

// ---------------- task-head packing (Wcat, bcat, ascat, adcat) -------------
// PADDED 224-channel layout: segments at {0,12,44,104}, pad cols 42,43 zero.

__global__ void pack_w_kernel(const float* __restrict__ wTL, const float* __restrict__ wYL,
                              const float* __restrict__ wTS, const float* __restrict__ wTZ,
                              const float* __restrict__ bTL, const float* __restrict__ bYL,
                              const float* __restrict__ bTS, const float* __restrict__ bTZ,
                              const float* __restrict__ asTL, const float* __restrict__ asYL,
                              const float* __restrict__ asTS, const float* __restrict__ asTZ,
                              const float* __restrict__ adTL, const float* __restrict__ adYL,
                              const float* __restrict__ adTS, const float* __restrict__ adTZ,
                              float* __restrict__ Wcat, float* __restrict__ bcat,
                              float* __restrict__ ascat, float* __restrict__ adcat) {
    int idx = blockIdx.x * blockDim.x + threadIdx.x;
    if (idx < 256 * 224) {
        int r = idx / 224, c = idx % 224;
        float v = 0.f;
        if (c < 12)       v = wTL[r * 12 + c];
        else if (c < 42)  v = wYL[r * 30 + (c - 12)];
        else if (c < 44)  v = 0.f;
        else if (c < 104) v = wTS[r * 60 + (c - 44)];
        else              v = wTZ[r * 120 + (c - 104)];
        Wcat[idx] = v;
    }
    if (idx < 224) {
        float b = 0.f, as_ = 0.f, ad_ = 0.f;
        if (idx < 12)       { b = bTL[idx];       as_ = asTL[idx];       ad_ = adTL[idx]; }
        else if (idx < 42)  { b = bYL[idx - 12];  as_ = asYL[idx - 12];  ad_ = adYL[idx - 12]; }
        else if (idx < 44)  { }
        else if (idx < 104) { b = bTS[idx - 44];  as_ = asTS[idx - 44];  ad_ = adTS[idx - 44]; }
        else                { b = bTZ[idx - 104]; as_ = asTZ[idx - 104]; ad_ = adTZ[idx - 104]; }
        bcat[idx]  = b;
        ascat[idx] = as_;
        adcat[idx] = ad_;
    }
}

// ---------------- 4-task gather + fused log_softmax (register-only) --------
// Padded 224-ch layout: lane*4 channels lie in exactly ONE task segment.
// Edge weight inline: w = exp(leaky(ast[s*4+t] + adt[wid*4+t])); pad w=0.
// Lanes 56-63 (no valid channels) clamp ch0 -> 0: no extra cachelines.

__device__ __forceinline__ float sel4(int t, float v0, float v1, float v2, float v3) {
    return (t == 0) ? v0 : (t == 1) ? v1 : (t == 2) ? v2 : v3;
}

__global__ __launch_bounds__(256) void task_gather_ls_kernel(
        const short* __restrict__ htb,
        const float* __restrict__ ast, const float* __restrict__ adt,
        const int* __restrict__ rowstart, const int* __restrict__ csr,
        const float* __restrict__ bcat, float* __restrict__ out, int n) {
    int wid  = blockIdx.x * 4 + (threadIdx.x >> 6);
    int lane = threadIdx.x & 63;
    if (wid >= n) return;
    int row = rowstart[wid];
    int pdeg = rowstart[wid + 1] - row;
    int ch0 = (lane < 56) ? lane * 4 : 0;
    int t = (lane < 3) ? 0 : (lane < 11) ? 1 : (lane < 26) ? 2 : 3;
    int COp = (t == 0) ? 0 : (t == 1) ? 12 : (t == 2) ? 44 : 104;   // padded start
    int COr = (t == 0) ? 0 : (t == 1) ? 12 : (t == 2) ? 42 : 102;   // real out offset
    int CLr = (t == 0) ? 12 : (t == 1) ? 30 : (t == 2) ? 60 : 120;  // real length
    bool valj[4];
    #pragma unroll
    for (int j = 0; j < 4; ++j)
        valj[j] = (unsigned)(ch0 + j - COp) < (unsigned)CLr;

    const int* cp = csr + row;
    float adtd = adt[(size_t)wid * 4 + t];

    float acc[4] = {0.f, 0.f, 0.f, 0.f};
    float wsv = 0.f;
    for (int base = 0; base < pdeg; base += 64) {
        int cnt = min(pdeg - base, 64);
        int idxv = -1;
        if (lane < cnt) idxv = cp[base + lane];
        int e = 0;
        for (; e + 8 <= cnt; e += 8) {
            int raw[8], si[8];
            #pragma unroll
            for (int i = 0; i < 8; ++i) {
                raw[i] = __builtin_amdgcn_readlane(idxv, e + i);
                si[i] = raw[i] < 0 ? 0 : raw[i];
            }
            float av[8];
            #pragma unroll
            for (int i = 0; i < 8; ++i)
                av[i] = ast[(size_t)si[i] * 4 + t];
            s4v hv[8];
            #pragma unroll
            for (int i = 0; i < 8; ++i)
                hv[i] = *(const s4v*)(htb + (size_t)si[i] * 224 + ch0);
            #pragma unroll
            for (int i = 0; i < 8; ++i) {
                float wgt = __expf(leaky(av[i] + adtd));
                if (raw[i] < 0) wgt = 0.f;
                float4 h = bf4_to_f4(hv[i]);
                acc[0] += wgt * h.x; acc[1] += wgt * h.y;
                acc[2] += wgt * h.z; acc[3] += wgt * h.w;
                wsv += wgt;
            }
        }
        for (; e < cnt; e += 4) {        // runs at most once (rows padded x4)
            int raw[4], si[4];
            #pragma unroll
            for (int i = 0; i < 4; ++i) {
                raw[i] = __builtin_amdgcn_readlane(idxv, e + i);
                si[i] = raw[i] < 0 ? 0 : raw[i];
            }
            float av[4];
            #pragma unroll
            for (int i = 0; i < 4; ++i)
                av[i] = ast[(size_t)si[i] * 4 + t];
            s4v hv[4];
            #pragma unroll
            for (int i = 0; i < 4; ++i)
                hv[i] = *(const s4v*)(htb + (size_t)si[i] * 224 + ch0);
            #pragma unroll
            for (int i = 0; i < 4; ++i) {
                float wgt = __expf(leaky(av[i] + adtd));
                if (raw[i] < 0) wgt = 0.f;
                float4 h = bf4_to_f4(hv[i]);
                acc[0] += wgt * h.x; acc[1] += wgt * h.y;
                acc[2] += wgt * h.z; acc[3] += wgt * h.w;
                wsv += wgt;
            }
        }
    }
    float inv = 1.f / (wsv + 1e-16f);

    // normalized logits; per-lane max for its (single) task
    float vout[4];
    float m = -1e30f;
    #pragma unroll
    for (int j = 0; j < 4; ++j) {
        float v = 0.f;
        if (valj[j]) { v = acc[j] * inv + bcat[ch0 + j]; m = fmaxf(m, v); }
        vout[j] = v;
    }
    float m0 = (t == 0) ? m : -1e30f;
    float m1 = (t == 1) ? m : -1e30f;
    float m2 = (t == 2) ? m : -1e30f;
    float m3 = (t == 3) ? m : -1e30f;
    #pragma unroll
    for (int off = 1; off < 64; off <<= 1) {
        m0 = fmaxf(m0, __shfl_xor(m0, off));
        m1 = fmaxf(m1, __shfl_xor(m1, off));
        m2 = fmaxf(m2, __shfl_xor(m2, off));
        m3 = fmaxf(m3, __shfl_xor(m3, off));
    }
    float mt = sel4(t, m0, m1, m2, m3);
    float sacc = 0.f;
    #pragma unroll
    for (int j = 0; j < 4; ++j)
        if (valj[j]) sacc += __expf(vout[j] - mt);
    float s0 = (t == 0) ? sacc : 0.f;
    float s1 = (t == 1) ? sacc : 0.f;
    float s2 = (t == 2) ? sacc : 0.f;
    float s3 = (t == 3) ? sacc : 0.f;
    #pragma unroll
    for (int off = 1; off < 64; off <<= 1) {
        s0 += __shfl_xor(s0, off);
        s1 += __shfl_xor(s1, off);
        s2 += __shfl_xor(s2, off);
        s3 += __shfl_xor(s3, off);
    }
    float st = sel4(t, s0, s1, s2, s3);
    float lse = mt + __logf(st);
    #pragma unroll
    for (int j = 0; j < 4; ++j)
        if (valj[j])
            out[(size_t)COr * n + (size_t)wid * CLr + (ch0 + j - COp)] = vout[j] - lse;
}

// ---------------- launcher ----------------

extern "C" void kernel_launch(void* const* d_in, const int* in_sizes, int n_in,
                              void* d_out, int out_size, void* d_ws, size_t ws_size,
                              hipStream_t stream) {
    const float* x   = (const float*)d_in[0];
    const int*   ei  = (const int*)d_in[1];
    const float* W1  = (const float*)d_in[2];
    const float* a1s = (const float*)d_in[3];
    const float* a1d = (const float*)d_in[4];
    const float* b1  = (const float*)d_in[5];
    const float* W2  = (const float*)d_in[6];
    const float* a2s = (const float*)d_in[7];
    const float* a2d = (const float*)d_in[8];
    const float* b2  = (const float*)d_in[9];
    const float* W_TL = (const float*)d_in[10]; const float* as_TL = (const float*)d_in[11];
    const float* ad_TL = (const float*)d_in[12]; const float* b_TL = (const float*)d_in[13];
    const float* W_YL = (const float*)d_in[14]; const float* as_YL = (const float*)d_in[15];
    const float* ad_YL = (const float*)d_in[16]; const float* b_YL = (const float*)d_in[17];
    const float* W_TS = (const float*)d_in[18]; const float* as_TS = (const float*)d_in[19];
    const float* ad_TS = (const float*)d_in[20]; const float* b_TS = (const float*)d_in[21];
    const float* W_TZ = (const float*)d_in[22]; const float* as_TZ = (const float*)d_in[23];
    const float* ad_TZ = (const float*)d_in[24]; const float* b_TZ = (const float*)d_in[25];

    const int N = in_sizes[0] / 128;
    const int E = in_sizes[1] / 2;
    const int* e_src = ei;
    const int* e_dst = ei + E;
    const int M4 = E + 4 * N;              // padded CSR slot bound (rows x4)

    float* ws = (float*)d_ws;
    float* B1   = ws;
    float* B2   = B1 + (size_t)N * 256;
    float* B3   = B2 + (size_t)N * 256;
    float* as1  = B3 + (size_t)N * 256;    // N*8
    float* ad1  = as1 + (size_t)N * 8;
    float* as2  = ad1 + (size_t)N * 8;
    float* ad2  = as2 + (size_t)N * 8;
    float* ast  = ad2 + (size_t)N * 8;     // N*4
    float* adt  = ast + (size_t)N * 4;
    float* Wcat = adt + (size_t)N * 4;     // 256*224 (padded task layout)
    float* bcat = Wcat + 256 * 224;        // 224
    float* ascat = bcat + 224;
    float* adcat = ascat + 224;
    int* deg      = (int*)(adcat + 224);   // N
    int* rowstart = deg + N;               // N+1 (cap N+4, keeps csr 16B-aligned)
    int* cursor   = rowstart + (N + 4);    // N
    int* csr      = cursor + N;            // M4 (16B-aligned)
    uintptr_t wsp = (uintptr_t)(csr + M4);
    wsp = (wsp + 15) & ~(uintptr_t)15;
    short* W1h = (short*)wsp;              // 272*128 (256 feat + 16 alpha)
    short* W1l = W1h + 272 * 128;
    short* W2h = W1l + 272 * 128;          // 272*256
    short* W2l = W2h + 272 * 256;
    short* Wth = W2l + 272 * 256;          // 232*256 (224 feat + 8 alpha)
    short* Wtl = Wth + 232 * 256;
    // overlays
    short* Xh  = (short*)B1;               // N*128
    short* Sh  = (short*)B1;               // N*256
    short* Th  = (short*)B1;               // N*256
    short* h1b = (short*)B2;               // stride 256
    short* h2b = (short*)B2;               // stride 256
    short* htb = (short*)B2;               // stride 224

    float* out = (float*)d_out;

    const int B = 256;
    // --- CSR build (padded rows) ---
    init_kernel<<<(N + B - 1) / B, B, 0, stream>>>(deg, cursor, N);
    count_kernel<<<(E + B - 1) / B, B, 0, stream>>>(e_dst, deg, E);
    scan_kernel<<<1, 1024, 0, stream>>>(deg, rowstart, N);
    hipMemsetAsync(csr, 0xFF, (size_t)M4 * sizeof(int), stream);   // csr = -1 (pads)
    scatter_kernel<<<(E + N + B - 1) / B, B, 0, stream>>>(e_src, e_dst, rowstart, cursor, csr, E, N);
    // --- pack + split + fold weights ---
    pack_w_kernel<<<(256 * 224 + B - 1) / B, B, 0, stream>>>(W_TL, W_YL, W_TS, W_TZ,
        b_TL, b_YL, b_TS, b_TZ, as_TL, as_YL, as_TS, as_TZ, ad_TL, ad_YL, ad_TS, ad_TZ,
        Wcat, bcat, ascat, adcat);
    split_bt_kernel<<<(256 * 128 + B - 1) / B, B, 0, stream>>>(W1, W1h, W1l, 128, 256, 7);
    split_bt_kernel<<<(256 * 256 + B - 1) / B, B, 0, stream>>>(W2, W2h, W2l, 256, 256, 8);
    split_bt_kernel<<<(224 * 256 + B - 1) / B, B, 0, stream>>>(Wcat, Wth, Wtl, 256, 224, 8);
    fold_alpha8_kernel<<<(128 * 16 + B - 1) / B, B, 0, stream>>>(W1, a1s, a1d, W1h, W1l, 128, 256);
    fold_alpha8_kernel<<<(256 * 16 + B - 1) / B, B, 0, stream>>>(W2, a2s, a2d, W2h, W2l, 256, 256);
    fold_alpha4_kernel<<<(256 * 8 + B - 1) / B, B, 0, stream>>>(Wcat, ascat, adcat, Wth, Wtl);
    // --- conv1: GEMM emits h1b bf16 + als1/ald1 directly ---
    tobf_kernel<<<((N * 128 / 4) + B - 1) / B, B, 0, stream>>>(x, Xh, N * 128 / 4);
    {
        dim3 g((272 + NB - 1) / NB, (N + MB - 1) / MB);
        gemm_mfma_kernel<<<g, 256, 0, stream>>>(Xh, W1h, W1l, h1b, 256,
                                                as1, ad1, 8, N, 128, 256, 272);
    }
    gat_gather_kernel<<<(N + 3) / 4, 256, 0, stream>>>(h1b, as1, ad1, rowstart, csr, b1, Sh, N, 1);
    // --- conv2 ---
    {
        dim3 g((272 + NB - 1) / NB, (N + MB - 1) / MB);
        gemm_mfma_kernel<<<g, 256, 0, stream>>>(Sh, W2h, W2l, h2b, 256,
                                                as2, ad2, 8, N, 256, 256, 272);
    }
    gat_gather_kernel<<<(N + 3) / 4, 256, 0, stream>>>(h2b, as2, ad2, rowstart, csr, b2, Th, N, 0);
    // --- task heads: GEMM emits htb bf16 (stride 224, padded) + ast/adt ---
    {
        dim3 g((232 + NB - 1) / NB, (N + MB - 1) / MB);
        gemm_mfma_kernel<<<g, 256, 0, stream>>>(Th, Wth, Wtl, htb, 224,
                                                ast, adt, 4, N, 256, 224, 232);
    }
    task_gather_ls_kernel<<<(N + 3) / 4, 256, 0, stream>>>(htb, ast, adt, rowstart, csr, bcat, out, N);
}

// Round 6
// 595.228 us; speedup vs baseline: 1.0607x; 1.0021x over previous
//
#include <hip/hip_runtime.h>
#include <math.h>

// ---------------------------------------------------------------------------
// MultiTaskGAT: 2x GATConv(8 heads x 32ch, concat) + 4 task heads (1 head)
// N=50000 nodes, E=800000 edges (+N self loops), F_IN=128, DH=256.
//
// R4: GEMMs -> bf16 MFMA hi/lo split.
// R6: alphas folded into GEMM B-columns; log_softmax fused into task gather.
// R8: CSR rows padded to x4; shuffle-based scan kernel.
// R9: per-wave CSR index preload (1 coalesced load + v_readlane); task
//     channel layout padded to 224; 8-edge groups, loads issued ahead.
// R11: edge-weight kernels fused into gathers (deleted ew8/ew4/csrd and the
//     ~80MB round-trip) -- but the inline exp was duplicated per lane and
//     regressed the gathers (VALU+trans critical path).
// R12: cooperative edge weights: per 8-edge group each lane PRODUCES one
//     (edge, head|task) weight (1 shfl for the edge src + 1 coalesced
//     als gather + 1 exp on one lane instead of 8) and consumers fetch via
//     8 shfl/bpermute on the idle LDS pipe. VMEM instrs/group 16->9,
//     trans 8->1, VALU -~30/group.
// R14: third submission of R12 (rounds 4/5 were container-acquisition
//     failures; same signature as round 1 which passed on resubmit).
// ---------------------------------------------------------------------------

#define NEG_SLOPE 0.2f

typedef short s8v __attribute__((ext_vector_type(8)));
typedef short s4v __attribute__((ext_vector_type(4)));
typedef float f4v __attribute__((ext_vector_type(4)));

__device__ __forceinline__ short f2bf(float x) {
    unsigned u = __float_as_uint(x);
    u += 0x7fffu + ((u >> 16) & 1u);
    return (short)(u >> 16);
}
__device__ __forceinline__ float bf2f(short b) {
    return __uint_as_float(((unsigned)(unsigned short)b) << 16);
}
__device__ __forceinline__ void split2(float x, short& h, short& l) {
    h = f2bf(x);
    l = f2bf(x - bf2f(h));
}
__device__ __forceinline__ float4 bf4_to_f4(s4v v) {
    return make_float4(bf2f(v[0]), bf2f(v[1]), bf2f(v[2]), bf2f(v[3]));
}
// leaky_relu(x) == max(x, 0.2x) for slope<1
__device__ __forceinline__ float leaky(float x) {
    return fmaxf(x, NEG_SLOPE * x);
}

// ---------------- CSR build ----------------

__global__ void init_kernel(int* __restrict__ deg, int* __restrict__ cursor, int n) {
    int i = blockIdx.x * blockDim.x + threadIdx.x;
    if (i < n) { deg[i] = 1; cursor[i] = 0; }   // deg starts at 1: self loop
}

__global__ void count_kernel(const int* __restrict__ dst, int* __restrict__ deg, int E) {
    int i = blockIdx.x * blockDim.x + threadIdx.x;
    if (i < E) atomicAdd(&deg[dst[i]], 1);
}

// scan of padded degrees ((deg+3)&~3) — shuffle-based, 3 barriers/iter
__global__ __launch_bounds__(1024) void scan_kernel(const int* __restrict__ deg,
                                                    int* __restrict__ rowstart, int n) {
    __shared__ int wsum[16];
    __shared__ int carry_sh;
    int lane = threadIdx.x & 63, wv = threadIdx.x >> 6;
    if (threadIdx.x == 0) { carry_sh = 0; rowstart[0] = 0; }
    __syncthreads();
    for (int base = 0; base < n; base += 8192) {
        int vals[8];
        int sum = 0;
        int i0 = base + threadIdx.x * 8;
        #pragma unroll
        for (int j = 0; j < 8; ++j) {
            int i = i0 + j;
            int v = (i < n) ? ((deg[i] + 3) & ~3) : 0;
            sum += v;
            vals[j] = sum;               // local inclusive
        }
        int incl = sum;
        #pragma unroll
        for (int off = 1; off < 64; off <<= 1) {
            int t = __shfl_up(incl, off);
            if (lane >= off) incl += t;
        }
        if (lane == 63) wsum[wv] = incl;
        __syncthreads();
        if (wv == 0) {
            int s = (lane < 16) ? wsum[lane] : 0;
            #pragma unroll
            for (int off = 1; off < 16; off <<= 1) {
                int t = __shfl_up(s, off);
                if (lane >= off) s += t;
            }
            if (lane < 16) wsum[lane] = s;
        }
        __syncthreads();
        int wexcl = (wv == 0) ? 0 : wsum[wv - 1];
        int excl = carry_sh + wexcl + (incl - sum);
        #pragma unroll
        for (int j = 0; j < 8; ++j) {
            int i = i0 + j;
            if (i < n) rowstart[i + 1] = excl + vals[j];
        }
        __syncthreads();
        if (threadIdx.x == 0) carry_sh += wsum[15];
        __syncthreads();
    }
}

__global__ void scatter_kernel(const int* __restrict__ src, const int* __restrict__ dst,
                               const int* __restrict__ rowstart, int* __restrict__ cursor,
                               int* __restrict__ csr, int E, int n) {
    int i = blockIdx.x * blockDim.x + threadIdx.x;
    if (i >= E + n) return;
    int s, d;
    if (i < E) { s = src[i]; d = dst[i]; }
    else       { s = d = i - E; }          // self loop
    int p = atomicAdd(&cursor[d], 1);
    csr[rowstart[d] + p] = s;
}

// ---------------- bf16 conversions / splits ----------------

__global__ void tobf_kernel(const float* __restrict__ A, short* __restrict__ Ah, int n4) {
    int i = blockIdx.x * blockDim.x + threadIdx.x;
    if (i >= n4) return;
    float4 v = ((const float4*)A)[i];
    s4v hv = {f2bf(v.x), f2bf(v.y), f2bf(v.z), f2bf(v.w)};
    ((s4v*)Ah)[i] = hv;
}

// B[K][Nc] fp32 -> Bt[n][k] bf16 hi/lo (k-contiguous for MFMA B-fragments)
__global__ void split_bt_kernel(const float* __restrict__ B, short* __restrict__ Bh,
                                short* __restrict__ Bl, int K, int Nc, int kshift) {
    int idx = blockIdx.x * blockDim.x + threadIdx.x;
    if (idx >= Nc * K) return;
    int n = idx >> kshift;          // K is a power of two (128/256)
    int k = idx & (K - 1);
    float v = B[(size_t)k * Nc + n];
    short h, l; split2(v, h, l);
    Bh[idx] = h;
    Bl[idx] = l;
}

// fold alphas into extra B-columns: col Nfeat+j (j<8: a_s head j, j>=8: a_d)
__global__ void fold_alpha8_kernel(const float* __restrict__ W,
                                   const float* __restrict__ a_s, const float* __restrict__ a_d,
                                   short* __restrict__ Bth, short* __restrict__ Btl,
                                   int K, int Nfeat) {
    int idx = blockIdx.x * blockDim.x + threadIdx.x;
    if (idx >= K * 16) return;
    int j = idx / K, k = idx % K;
    int h = j & 7;
    const float* av = ((j < 8) ? a_s : a_d) + h * 32;
    const float* wp = W + (size_t)k * 256 + h * 32;
    float s = 0.f;
    #pragma unroll
    for (int c = 0; c < 32; ++c) s += wp[c] * av[c];
    short hi, lo; split2(s, hi, lo);
    size_t off = (size_t)(Nfeat + j) * K + k;
    Bth[off] = hi; Btl[off] = lo;
}

// task version: 4 tasks, PADDED segments over 224 channels, K=256.
// segment starts {0,12,44,104}, padded lengths {12,32,60,120} (pads hold
// zero W and zero alpha -> contribute 0).
__global__ void fold_alpha4_kernel(const float* __restrict__ Wcat,
                                   const float* __restrict__ ascat, const float* __restrict__ adcat,
                                   short* __restrict__ Bth, short* __restrict__ Btl) {
    int idx = blockIdx.x * blockDim.x + threadIdx.x;
    if (idx >= 256 * 8) return;
    int j = idx >> 8, k = idx & 255;
    const int CO[4] = {0, 12, 44, 104};
    const int CL[4] = {12, 32, 60, 120};
    int t = j & 3;
    const float* av = ((j < 4) ? ascat : adcat) + CO[t];
    const float* wp = Wcat + (size_t)k * 224 + CO[t];
    float s = 0.f;
    for (int c = 0; c < CL[t]; ++c) s += wp[c] * av[c];
    short hi, lo; split2(s, hi, lo);
    size_t off = (size_t)(224 + j) * 256 + k;
    Bth[off] = hi; Btl[off] = lo;
}

// ---------------- bf16 MFMA GEMM + fused alpha output ----------------------

#define MB 128
#define NB 64
#define KS 32

__global__ __launch_bounds__(256) void gemm_mfma_kernel(
        const short* __restrict__ Ah_g,
        const short* __restrict__ Bth_g, const short* __restrict__ Btl_g,
        short* __restrict__ Cb, int cb_stride,
        float* __restrict__ als, float* __restrict__ ald, int nsplit,
        int M, int K, int Nfeat, int NcExt) {
    __shared__ __align__(16) short Ah[MB][40];
    __shared__ __align__(16) short Bh[NB][40];
    __shared__ __align__(16) short Bl[NB][40];

    int t = threadIdx.x;
    int lane = t & 63, w = t >> 6;
    int quad = lane >> 4, l16 = lane & 15;
    int row0 = blockIdx.y * MB, col0 = blockIdx.x * NB;

    f4v acc[2][4];
    #pragma unroll
    for (int mt = 0; mt < 2; ++mt)
        #pragma unroll
        for (int nt = 0; nt < 4; ++nt)
            acc[mt][nt] = (f4v){0.f, 0.f, 0.f, 0.f};

    for (int k0 = 0; k0 < K; k0 += KS) {
        __syncthreads();
        #pragma unroll
        for (int i = 0; i < 2; ++i) {
            int u = i * 256 + t;
            int r = u >> 2, kk = (u & 3) * 8;
            int gr = row0 + r;
            s8v vh = {0, 0, 0, 0, 0, 0, 0, 0};
            if (gr < M) vh = *(const s8v*)(Ah_g + (size_t)gr * K + k0 + kk);
            *(s8v*)&Ah[r][kk] = vh;
        }
        {
            int n = t >> 2, kk = (t & 3) * 8;
            int gc = col0 + n;
            s8v vh = {0, 0, 0, 0, 0, 0, 0, 0};
            s8v vl = {0, 0, 0, 0, 0, 0, 0, 0};
            if (gc < NcExt) {
                vh = *(const s8v*)(Bth_g + (size_t)gc * K + k0 + kk);
                vl = *(const s8v*)(Btl_g + (size_t)gc * K + k0 + kk);
            }
            *(s8v*)&Bh[n][kk] = vh;
            *(s8v*)&Bl[n][kk] = vl;
        }
        __syncthreads();

        int kb = quad * 8;
        s8v a_f[2], b_h[4], b_l[4];
        #pragma unroll
        for (int mt = 0; mt < 2; ++mt) {
            int r = w * 32 + mt * 16 + l16;
            a_f[mt] = *(const s8v*)&Ah[r][kb];
        }
        #pragma unroll
        for (int nt = 0; nt < 4; ++nt) {
            int c = nt * 16 + l16;
            b_h[nt] = *(const s8v*)&Bh[c][kb];
            b_l[nt] = *(const s8v*)&Bl[c][kb];
        }
        #pragma unroll
        for (int mt = 0; mt < 2; ++mt)
            #pragma unroll
            for (int nt = 0; nt < 4; ++nt) {
                acc[mt][nt] = __builtin_amdgcn_mfma_f32_16x16x32_bf16(
                    a_f[mt], b_h[nt], acc[mt][nt], 0, 0, 0);
                acc[mt][nt] = __builtin_amdgcn_mfma_f32_16x16x32_bf16(
                    a_f[mt], b_l[nt], acc[mt][nt], 0, 0, 0);
            }
    }

    // epilogue: C/D layout col=lane&15, row=quad*4+reg
    #pragma unroll
    for (int mt = 0; mt < 2; ++mt) {
        #pragma unroll
        for (int nt = 0; nt < 4; ++nt) {
            int gc = col0 + nt * 16 + l16;
            if (gc >= NcExt) continue;
            #pragma unroll
            for (int r = 0; r < 4; ++r) {
                int gr = row0 + w * 32 + mt * 16 + quad * 4 + r;
                if (gr >= M) continue;
                float v = acc[mt][nt][r];
                if (gc < Nfeat) {
                    Cb[(size_t)gr * cb_stride + gc] = f2bf(v);
                } else {
                    int j = gc - Nfeat;
                    if (j < nsplit)            als[(size_t)gr * nsplit + j] = v;
                    else if (j < 2 * nsplit)   ald[(size_t)gr * nsplit + (j - nsplit)] = v;
                }
            }
        }
    }
}

// ---------------- GAT gather (8 heads x 32 ch), one wave per dst -----------
// Cooperative edge weights: per 8-edge group, producer lane l computes the
// weight for edge (l>>3), head (l&7) -- one shfl + one coalesced als gather
// + one exp -- consumers fetch their 8 weights via shfl (LDS pipe).

__global__ __launch_bounds__(256) void gat_gather_kernel(
        const short* __restrict__ hb,
        const float* __restrict__ als, const float* __restrict__ ald,
        const int* __restrict__ rowstart, const int* __restrict__ csr,
        const float* __restrict__ bias, short* __restrict__ oh, int n, int elu) {
    int wid  = blockIdx.x * 4 + (threadIdx.x >> 6);
    int lane = threadIdx.x & 63;
    if (wid >= n) return;
    int row = rowstart[wid];
    int pdeg = rowstart[wid + 1] - row;
    int hp = lane >> 3;              // consumer head
    int ch = lane * 4;
    int ph = lane & 7;               // producer head
    const int* cp = csr + row;
    float aldv = ald[(size_t)wid * 8 + ph];   // producer-side dst alpha

    float4 acc = {0.f, 0.f, 0.f, 0.f};
    float wsum = 0.f;
    for (int base = 0; base < pdeg; base += 64) {
        int cnt = min(pdeg - base, 64);
        int idxv = -1;
        if (lane < cnt) idxv = cp[base + lane];
        int e = 0;
        for (; e + 8 <= cnt; e += 8) {
            int si[8];
            #pragma unroll
            for (int i = 0; i < 8; ++i) {
                int r = __builtin_amdgcn_readlane(idxv, e + i);
                si[i] = r < 0 ? 0 : r;
            }
            s4v hv[8];
            #pragma unroll
            for (int i = 0; i < 8; ++i)
                hv[i] = *(const s4v*)(hb + (size_t)si[i] * 256 + ch);
            // producer: weight for (edge lane>>3, head lane&7)
            int sprod = __shfl(idxv, e + (lane >> 3));
            int sp = sprod < 0 ? 0 : sprod;
            float wall = __expf(leaky(als[(size_t)sp * 8 + ph] + aldv));
            if (sprod < 0) wall = 0.f;
            float w[8];
            #pragma unroll
            for (int i = 0; i < 8; ++i) w[i] = __shfl(wall, i * 8 + hp);
            #pragma unroll
            for (int i = 0; i < 8; ++i) {
                float4 h = bf4_to_f4(hv[i]);
                acc.x += w[i] * h.x; acc.y += w[i] * h.y;
                acc.z += w[i] * h.z; acc.w += w[i] * h.w;
                wsum += w[i];
            }
        }
        if (e < cnt) {                   // 4-edge tail, at most once
            int si[4];
            #pragma unroll
            for (int i = 0; i < 4; ++i) {
                int r = __builtin_amdgcn_readlane(idxv, e + i);
                si[i] = r < 0 ? 0 : r;
            }
            s4v hv[4];
            #pragma unroll
            for (int i = 0; i < 4; ++i)
                hv[i] = *(const s4v*)(hb + (size_t)si[i] * 256 + ch);
            int sprod = __shfl(idxv, e + ((lane >> 3) & 3));
            int sp = sprod < 0 ? 0 : sprod;
            float wall = __expf(leaky(als[(size_t)sp * 8 + ph] + aldv));
            if (sprod < 0) wall = 0.f;
            float w[4];
            #pragma unroll
            for (int i = 0; i < 4; ++i) w[i] = __shfl(wall, i * 8 + hp);
            #pragma unroll
            for (int i = 0; i < 4; ++i) {
                float4 h = bf4_to_f4(hv[i]);
                acc.x += w[i] * h.x; acc.y += w[i] * h.y;
                acc.z += w[i] * h.z; acc.w += w[i] * h.w;
                wsum += w[i];
            }
        }
    }
    float inv = 1.f / (wsum + 1e-16f);
    float4 b4 = *(const float4*)(bias + ch);
    float v[4] = {acc.x * inv + b4.x, acc.y * inv + b4.y,
                  acc.z * inv + b4.z, acc.w * inv + b4.w};
    if (elu) {
        #pragma unroll
        for (int j = 0; j < 4; ++j)
            v[j] = (v[j] > 0.f) ? v[j] : __expf(v[j]) - 1.f;
    }
    s4v hvo = {f2bf(v[0]), f2bf(v[1]), f2bf(v[2]), f2bf(v[3])};
    *(s4v*)(oh + (size_t)wid * 256 + ch) = hvo;
}

// ---------------- task-head packing (Wcat, bcat, ascat, adcat) -------------
// PADDED 224-channel layout: segments at {0,12,44,104}, pad cols 42,43 zero.

__global__ void pack_w_kernel(const float* __restrict__ wTL, const float* __restrict__ wYL,
                              const float* __restrict__ wTS, const float* __restrict__ wTZ,
                              const float* __restrict__ bTL, const float* __restrict__ bYL,
                              const float* __restrict__ bTS, const float* __restrict__ bTZ,
                              const float* __restrict__ asTL, const float* __restrict__ asYL,
                              const float* __restrict__ asTS, const float* __restrict__ asTZ,
                              const float* __restrict__ adTL, const float* __restrict__ adYL,
                              const float* __restrict__ adTS, const float* __restrict__ adTZ,
                              float* __restrict__ Wcat, float* __restrict__ bcat,
                              float* __restrict__ ascat, float* __restrict__ adcat) {
    int idx = blockIdx.x * blockDim.x + threadIdx.x;
    if (idx < 256 * 224) {
        int r = idx / 224, c = idx % 224;
        float v = 0.f;
        if (c < 12)       v = wTL[r * 12 + c];
        else if (c < 42)  v = wYL[r * 30 + (c - 12)];
        else if (c < 44)  v = 0.f;
        else if (c < 104) v = wTS[r * 60 + (c - 44)];
        else              v = wTZ[r * 120 + (c - 104)];
        Wcat[idx] = v;
    }
    if (idx < 224) {
        float b = 0.f, as_ = 0.f, ad_ = 0.f;
        if (idx < 12)       { b = bTL[idx];       as_ = asTL[idx];       ad_ = adTL[idx]; }
        else if (idx < 42)  { b = bYL[idx - 12];  as_ = asYL[idx - 12];  ad_ = adYL[idx - 12]; }
        else if (idx < 44)  { }
        else if (idx < 104) { b = bTS[idx - 44];  as_ = asTS[idx - 44];  ad_ = adTS[idx - 44]; }
        else                { b = bTZ[idx - 104]; as_ = asTZ[idx - 104]; ad_ = adTZ[idx - 104]; }
        bcat[idx]  = b;
        ascat[idx] = as_;
        adcat[idx] = ad_;
    }
}

// ---------------- 4-task gather + fused log_softmax (register-only) --------
// Padded 224-ch layout: lane*4 channels lie in exactly ONE task segment.
// Cooperative weights: producer lane l -> edge (l>>3), task (l&3).
// Lanes 56-63 (no valid channels) clamp ch0 -> 0: no extra cachelines.

__device__ __forceinline__ float sel4(int t, float v0, float v1, float v2, float v3) {
    return (t == 0) ? v0 : (t == 1) ? v1 : (t == 2) ? v2 : v3;
}

__global__ __launch_bounds__(256) void task_gather_ls_kernel(
        const short* __restrict__ htb,
        const float* __restrict__ ast, const float* __restrict__ adt,
        const int* __restrict__ rowstart, const int* __restrict__ csr,
        const float* __restrict__ bcat, float* __restrict__ out, int n) {
    int wid  = blockIdx.x * 4 + (threadIdx.x >> 6);
    int lane = threadIdx.x & 63;
    if (wid >= n) return;
    int row = rowstart[wid];
    int pdeg = rowstart[wid + 1] - row;
    int ch0 = (lane < 56) ? lane * 4 : 0;
    int t = (lane < 3) ? 0 : (lane < 11) ? 1 : (lane < 26) ? 2 : 3;
    int pt = lane & 3;               // producer task
    int COp = (t == 0) ? 0 : (t == 1) ? 12 : (t == 2) ? 44 : 104;   // padded start
    int COr = (t == 0) ? 0 : (t == 1) ? 12 : (t == 2) ? 42 : 102;   // real out offset
    int CLr = (t == 0) ? 12 : (t == 1) ? 30 : (t == 2) ? 60 : 120;  // real length
    bool valj[4];
    #pragma unroll
    for (int j = 0; j < 4; ++j)
        valj[j] = (unsigned)(ch0 + j - COp) < (unsigned)CLr;

    const int* cp = csr + row;
    float adtv = adt[(size_t)wid * 4 + pt];  // producer-side dst alpha

    float acc[4] = {0.f, 0.f, 0.f, 0.f};
    float wsv = 0.f;
    for (int base = 0; base < pdeg; base += 64) {
        int cnt = min(pdeg - base, 64);
        int idxv = -1;
        if (lane < cnt) idxv = cp[base + lane];
        int e = 0;
        for (; e + 8 <= cnt; e += 8) {
            int si[8];
            #pragma unroll
            for (int i = 0; i < 8; ++i) {
                int r = __builtin_amdgcn_readlane(idxv, e + i);
                si[i] = r < 0 ? 0 : r;
            }
            s4v hv[8];
            #pragma unroll
            for (int i = 0; i < 8; ++i)
                hv[i] = *(const s4v*)(htb + (size_t)si[i] * 224 + ch0);
            // producer: weight for (edge lane>>3, task lane&3)
            int sprod = __shfl(idxv, e + (lane >> 3));
            int sp = sprod < 0 ? 0 : sprod;
            float wall = __expf(leaky(ast[(size_t)sp * 4 + pt] + adtv));
            if (sprod < 0) wall = 0.f;
            float w[8];
            #pragma unroll
            for (int i = 0; i < 8; ++i) w[i] = __shfl(wall, i * 8 + t);
            #pragma unroll
            for (int i = 0; i < 8; ++i) {
                float4 h = bf4_to_f4(hv[i]);
                acc[0] += w[i] * h.x; acc[1] += w[i] * h.y;
                acc[2] += w[i] * h.z; acc[3] += w[i] * h.w;
                wsv += w[i];
            }
        }
        if (e < cnt) {                   // 4-edge tail, at most once
            int si[4];
            #pragma unroll
            for (int i = 0; i < 4; ++i) {
                int r = __builtin_amdgcn_readlane(idxv, e + i);
                si[i] = r < 0 ? 0 : r;
            }
            s4v hv[4];
            #pragma unroll
            for (int i = 0; i < 4; ++i)
                hv[i] = *(const s4v*)(htb + (size_t)si[i] * 224 + ch0);
            int sprod = __shfl(idxv, e + ((lane >> 3) & 3));
            int sp = sprod < 0 ? 0 : sprod;
            float wall = __expf(leaky(ast[(size_t)sp * 4 + pt] + adtv));
            if (sprod < 0) wall = 0.f;
            float w[4];
            #pragma unroll
            for (int i = 0; i < 4; ++i) w[i] = __shfl(wall, i * 8 + t);
            #pragma unroll
            for (int i = 0; i < 4; ++i) {
                float4 h = bf4_to_f4(hv[i]);
                acc[0] += w[i] * h.x; acc[1] += w[i] * h.y;
                acc[2] += w[i] * h.z; acc[3] += w[i] * h.w;
                wsv += w[i];
            }
        }
    }
    float inv = 1.f / (wsv + 1e-16f);

    // normalized logits; per-lane max for its (single) task
    float vout[4];
    float m = -1e30f;
    #pragma unroll
    for (int j = 0; j < 4; ++j) {
        float v = 0.f;
        if (valj[j]) { v = acc[j] * inv + bcat[ch0 + j]; m = fmaxf(m, v); }
        vout[j] = v;
    }
    float m0 = (t == 0) ? m : -1e30f;
    float m1 = (t == 1) ? m : -1e30f;
    float m2 = (t == 2) ? m : -1e30f;
    float m3 = (t == 3) ? m : -1e30f;
    #pragma unroll
    for (int off = 1; off < 64; off <<= 1) {
        m0 = fmaxf(m0, __shfl_xor(m0, off));
        m1 = fmaxf(m1, __shfl_xor(m1, off));
        m2 = fmaxf(m2, __shfl_xor(m2, off));
        m3 = fmaxf(m3, __shfl_xor(m3, off));
    }
    float mt = sel4(t, m0, m1, m2, m3);
    float sacc = 0.f;
    #pragma unroll
    for (int j = 0; j < 4; ++j)
        if (valj[j]) sacc += __expf(vout[j] - mt);
    float s0 = (t == 0) ? sacc : 0.f;
    float s1 = (t == 1) ? sacc : 0.f;
    float s2 = (t == 2) ? sacc : 0.f;
    float s3 = (t == 3) ? sacc : 0.f;
    #pragma unroll
    for (int off = 1; off < 64; off <<= 1) {
        s0 += __shfl_xor(s0, off);
        s1 += __shfl_xor(s1, off);
        s2 += __shfl_xor(s2, off);
        s3 += __shfl_xor(s3, off);
    }
    float st = sel4(t, s0, s1, s2, s3);
    float lse = mt + __logf(st);
    #pragma unroll
    for (int j = 0; j < 4; ++j)
        if (valj[j])
            out[(size_t)COr * n + (size_t)wid * CLr + (ch0 + j - COp)] = vout[j] - lse;
}

// ---------------- launcher ----------------

extern "C" void kernel_launch(void* const* d_in, const int* in_sizes, int n_in,
                              void* d_out, int out_size, void* d_ws, size_t ws_size,
                              hipStream_t stream) {
    const float* x   = (const float*)d_in[0];
    const int*   ei  = (const int*)d_in[1];
    const float* W1  = (const float*)d_in[2];
    const float* a1s = (const float*)d_in[3];
    const float* a1d = (const float*)d_in[4];
    const float* b1  = (const float*)d_in[5];
    const float* W2  = (const float*)d_in[6];
    const float* a2s = (const float*)d_in[7];
    const float* a2d = (const float*)d_in[8];
    const float* b2  = (const float*)d_in[9];
    const float* W_TL = (const float*)d_in[10]; const float* as_TL = (const float*)d_in[11];
    const float* ad_TL = (const float*)d_in[12]; const float* b_TL = (const float*)d_in[13];
    const float* W_YL = (const float*)d_in[14]; const float* as_YL = (const float*)d_in[15];
    const float* ad_YL = (const float*)d_in[16]; const float* b_YL = (const float*)d_in[17];
    const float* W_TS = (const float*)d_in[18]; const float* as_TS = (const float*)d_in[19];
    const float* ad_TS = (const float*)d_in[20]; const float* b_TS = (const float*)d_in[21];
    const float* W_TZ = (const float*)d_in[22]; const float* as_TZ = (const float*)d_in[23];
    const float* ad_TZ = (const float*)d_in[24]; const float* b_TZ = (const float*)d_in[25];

    const int N = in_sizes[0] / 128;
    const int E = in_sizes[1] / 2;
    const int* e_src = ei;
    const int* e_dst = ei + E;
    const int M4 = E + 4 * N;              // padded CSR slot bound (rows x4)

    float* ws = (float*)d_ws;
    float* B1   = ws;
    float* B2   = B1 + (size_t)N * 256;
    float* B3   = B2 + (size_t)N * 256;
    float* as1  = B3 + (size_t)N * 256;    // N*8
    float* ad1  = as1 + (size_t)N * 8;
    float* as2  = ad1 + (size_t)N * 8;
    float* ad2  = as2 + (size_t)N * 8;
    float* ast  = ad2 + (size_t)N * 8;     // N*4
    float* adt  = ast + (size_t)N * 4;
    float* Wcat = adt + (size_t)N * 4;     // 256*224 (padded task layout)
    float* bcat = Wcat + 256 * 224;        // 224
    float* ascat = bcat + 224;
    float* adcat = ascat + 224;
    int* deg      = (int*)(adcat + 224);   // N
    int* rowstart = deg + N;               // N+1 (cap N+4, keeps csr 16B-aligned)
    int* cursor   = rowstart + (N + 4);    // N
    int* csr      = cursor + N;            // M4 (16B-aligned)
    uintptr_t wsp = (uintptr_t)(csr + M4);
    wsp = (wsp + 15) & ~(uintptr_t)15;
    short* W1h = (short*)wsp;              // 272*128 (256 feat + 16 alpha)
    short* W1l = W1h + 272 * 128;
    short* W2h = W1l + 272 * 128;          // 272*256
    short* W2l = W2h + 272 * 256;
    short* Wth = W2l + 272 * 256;          // 232*256 (224 feat + 8 alpha)
    short* Wtl = Wth + 232 * 256;
    // overlays
    short* Xh  = (short*)B1;               // N*128
    short* Sh  = (short*)B1;               // N*256
    short* Th  = (short*)B1;               // N*256
    short* h1b = (short*)B2;               // stride 256
    short* h2b = (short*)B2;               // stride 256
    short* htb = (short*)B2;               // stride 224

    float* out = (float*)d_out;

    const int B = 256;
    // --- CSR build (padded rows) ---
    init_kernel<<<(N + B - 1) / B, B, 0, stream>>>(deg, cursor, N);
    count_kernel<<<(E + B - 1) / B, B, 0, stream>>>(e_dst, deg, E);
    scan_kernel<<<1, 1024, 0, stream>>>(deg, rowstart, N);
    hipMemsetAsync(csr, 0xFF, (size_t)M4 * sizeof(int), stream);   // csr = -1 (pads)
    scatter_kernel<<<(E + N + B - 1) / B, B, 0, stream>>>(e_src, e_dst, rowstart, cursor, csr, E, N);
    // --- pack + split + fold weights ---
    pack_w_kernel<<<(256 * 224 + B - 1) / B, B, 0, stream>>>(W_TL, W_YL, W_TS, W_TZ,
        b_TL, b_YL, b_TS, b_TZ, as_TL, as_YL, as_TS, as_TZ, ad_TL, ad_YL, ad_TS, ad_TZ,
        Wcat, bcat, ascat, adcat);
    split_bt_kernel<<<(256 * 128 + B - 1) / B, B, 0, stream>>>(W1, W1h, W1l, 128, 256, 7);
    split_bt_kernel<<<(256 * 256 + B - 1) / B, B, 0, stream>>>(W2, W2h, W2l, 256, 256, 8);
    split_bt_kernel<<<(224 * 256 + B - 1) / B, B, 0, stream>>>(Wcat, Wth, Wtl, 256, 224, 8);
    fold_alpha8_kernel<<<(128 * 16 + B - 1) / B, B, 0, stream>>>(W1, a1s, a1d, W1h, W1l, 128, 256);
    fold_alpha8_kernel<<<(256 * 16 + B - 1) / B, B, 0, stream>>>(W2, a2s, a2d, W2h, W2l, 256, 256);
    fold_alpha4_kernel<<<(256 * 8 + B - 1) / B, B, 0, stream>>>(Wcat, ascat, adcat, Wth, Wtl);
    // --- conv1: GEMM emits h1b bf16 + als1/ald1 directly ---
    tobf_kernel<<<((N * 128 / 4) + B - 1) / B, B, 0, stream>>>(x, Xh, N * 128 / 4);
    {
        dim3 g((272 + NB - 1) / NB, (N + MB - 1) / MB);
        gemm_mfma_kernel<<<g, 256, 0, stream>>>(Xh, W1h, W1l, h1b, 256,
                                                as1, ad1, 8, N, 128, 256, 272);
    }
    gat_gather_kernel<<<(N + 3) / 4, 256, 0, stream>>>(h1b, as1, ad1, rowstart, csr, b1, Sh, N, 1);
    // --- conv2 ---
    {
        dim3 g((272 + NB - 1) / NB, (N + MB - 1) / MB);
        gemm_mfma_kernel<<<g, 256, 0, stream>>>(Sh, W2h, W2l, h2b, 256,
                                                as2, ad2, 8, N, 256, 256, 272);
    }
    gat_gather_kernel<<<(N + 3) / 4, 256, 0, stream>>>(h2b, as2, ad2, rowstart, csr, b2, Th, N, 0);
    // --- task heads: GEMM emits htb bf16 (stride 224, padded) + ast/adt ---
    {
        dim3 g((232 + NB - 1) / NB, (N + MB - 1) / MB);
        gemm_mfma_kernel<<<g, 256, 0, stream>>>(Th, Wth, Wtl, htb, 224,
                                                ast, adt, 4, N, 256, 224, 232);
    }
    task_gather_ls_kernel<<<(N + 3) / 4, 256, 0, stream>>>(htb, ast, adt, rowstart, csr, bcat, out, N);
}